// Round 1
// baseline (128.548 us; speedup 1.0000x reference)
//
#include <hip/hip_runtime.h>

#define G_TOT 2016
#define NGB 126   // G_TOT / 16

typedef _Float16 f16;
typedef __attribute__((ext_vector_type(4))) _Float16 v4h;
typedef __attribute__((ext_vector_type(4))) float v4f;

// ---------------------------------------------------------------------------
// Prep: gather Y into MFMA-fragment-ordered f16 tables (coalesced b64 loads
// in the main loop). A1buf: A-operand of G1^T = Y^T frag (m=g, k=ksh).
// B2buf: B-operand of CO gemm = Yw frag (k=g, n=ksh), qw folded in.
// ---------------------------------------------------------------------------
__global__ void vg_prep(const float* __restrict__ Y, const float* __restrict__ qw,
                        f16* __restrict__ A1buf, f16* __restrict__ B2buf) {
    const int gb = blockIdx.x;
    const int lane = threadIdx.x & 63;
    const int lhi = lane >> 4, llo = lane & 15;
#pragma unroll
    for (int ks = 0; ks < 2; ++ks)
#pragma unroll
        for (int j = 0; j < 4; ++j) {
            const int ksh = ks * 16 + lhi * 4 + j;
            const int g = gb * 16 + llo;
            const float v = (ksh < 25) ? Y[ksh * G_TOT + g] : 0.0f;
            A1buf[((gb * 2 + ks) * 64 + lane) * 4 + j] = (f16)v;
        }
#pragma unroll
    for (int t = 0; t < 2; ++t)
#pragma unroll
        for (int j = 0; j < 4; ++j) {
            const int ksh = t * 16 + llo;
            const int g = gb * 16 + lhi * 4 + j;
            const float v = (ksh < 25) ? Y[ksh * G_TOT + g] * qw[g] : 0.0f;
            B2buf[((gb * 2 + t) * 64 + lane) * 4 + j] = (f16)v;
        }
}

// ---------------------------------------------------------------------------
// Main fused kernel: one block per (n, parity), 4 waves.
// Rows r = v*32 + c (96 rows). Row-tile Rn = 2*v + h (h = c-half).
// MFMA1 (swapped): D1[g][row] = sum_ksh Y[ksh][g] * h[row][ksh]
// cross in-register -> lands in A-fragment layout of MFMA2
// MFMA2: CO[row][ksh] += sum_g cr[row][g] * Yw[ksh][g]
// ---------------------------------------------------------------------------
template <bool USE_WS>
__global__ __launch_bounds__(256, 2)
void vg_main(const float* __restrict__ x1, const float* __restrict__ x2,
             const float* __restrict__ W1s, const float* __restrict__ W2s,
             const float* __restrict__ Wouts, const float* __restrict__ Y,
             const float* __restrict__ qw,
             const f16* __restrict__ A1buf, const f16* __restrict__ B2buf,
             float* __restrict__ out) {
    __shared__ __align__(16) char smem[31488];
    f16* hbuf = (f16*)smem;               // [2][96][32] f16 (k padded to 32 w/ zeros)
    float* xs = (float*)(smem + 12288);   // [2][2400] f32, phase 0 only
    float* cob = (float*)(smem + 12288);  // [96][32] f32, epilogue (reuses xs space)

    const int bid = blockIdx.x;
    const int n = bid / 3, p = bid % 3;
    const int tid = threadIdx.x;
    const int wid = tid >> 6;
    const int lane = tid & 63;
    const int lhi = lane >> 4, llo = lane & 15;

    // ---- phase 0a: stage x1[n], x2[n]; zero hbuf
    const float* x1n = x1 + n * 2400;
    const float* x2n = x2 + n * 2400;
    for (int i = tid; i < 2400; i += 256) {
        xs[i] = x1n[i];
        xs[2400 + i] = x2n[i];
    }
    for (int i = tid; i < 3072; i += 256) ((float*)hbuf)[i] = 0.0f;
    __syncthreads();

    // ---- phase 0b: h[row=v*32+c][k] = sum_f x[f,v,k] * W[l_k,f,c], cast f16
    {
        const int c = tid & 31, grp = tid >> 5;
        const float* W1p = W1s + p * 5120;
        const float* W2p = W2s + p * 5120;
        for (int vk = grp; vk < 75; vk += 8) {
            const int v = vk / 25, k = vk - v * 25;
            const int l = (k >= 16) ? 4 : (k >= 9) ? 3 : (k >= 4) ? 2 : (k >= 1) ? 1 : 0;
            const float* w1 = W1p + l * 1024 + c;
            const float* w2 = W2p + l * 1024 + c;
            float a1 = 0.0f, a2s = 0.0f;
#pragma unroll
            for (int f = 0; f < 32; ++f) {
                a1 += xs[f * 75 + vk] * w1[f * 32];
                a2s += xs[2400 + f * 75 + vk] * w2[f * 32];
            }
            const int row = v * 32 + c;
            hbuf[row * 32 + k] = (f16)a1;
            hbuf[3072 + row * 32 + k] = (f16)a2s;
        }
    }
    __syncthreads();

    // ---- hoisted h fragments (B-operand of MFMA1): B[k=4*lhi+j][n=llo]
    v4h hfrag[2][6][2];
#pragma unroll
    for (int s = 0; s < 2; ++s)
#pragma unroll
        for (int Rn = 0; Rn < 6; ++Rn)
#pragma unroll
            for (int ks = 0; ks < 2; ++ks)
                hfrag[s][Rn][ks] =
                    *(const v4h*)&hbuf[s * 3072 + (Rn * 16 + llo) * 32 + ks * 16 + lhi * 4];

    const v4f zero4 = {0.0f, 0.0f, 0.0f, 0.0f};
    v4f coacc[6][2];
#pragma unroll
    for (int Rn = 0; Rn < 6; ++Rn)
#pragma unroll
        for (int t = 0; t < 2; ++t) coacc[Rn][t] = zero4;

    // ---- main loop over g-blocks of 16 (waves independent)
    for (int gb = wid; gb < NGB; gb += 4) {
        v4h a1k0, a1k1, b20, b21;
        if constexpr (USE_WS) {
            const v4h* a1p = (const v4h*)(A1buf + gb * 512);
            a1k0 = a1p[lane];
            a1k1 = a1p[64 + lane];
            const v4h* b2p = (const v4h*)(B2buf + gb * 512);
            b20 = b2p[lane];
            b21 = b2p[64 + lane];
        } else {
            const int ga = gb * 16 + llo;
            const int gbr = gb * 16 + lhi * 4;
#pragma unroll
            for (int j = 0; j < 4; ++j) {
                const int k0 = lhi * 4 + j;
                a1k0[j] = (f16)Y[k0 * G_TOT + ga];
                const int k1 = 16 + lhi * 4 + j;
                a1k1[j] = (f16)((k1 < 25) ? Y[k1 * G_TOT + ga] : 0.0f);
                const float qg = qw[gbr + j];
                b20[j] = (f16)(Y[llo * G_TOT + gbr + j] * qg);
                const int kb = 16 + llo;
                b21[j] = (f16)((kb < 25) ? Y[kb * G_TOT + gbr + j] * qg : 0.0f);
            }
        }

        // MFMA1: accg[s][Rn] lane,j = G^T[g=gb*16+4*lhi+j][row=Rn*16+llo]
        v4f accg[2][6];
#pragma unroll
        for (int s = 0; s < 2; ++s)
#pragma unroll
            for (int Rn = 0; Rn < 6; ++Rn) {
                v4f z = zero4;
                z = __builtin_amdgcn_mfma_f32_16x16x16f16(a1k0, hfrag[s][Rn][0], z, 0, 0, 0);
                z = __builtin_amdgcn_mfma_f32_16x16x16f16(a1k1, hfrag[s][Rn][1], z, 0, 0, 0);
                accg[s][Rn] = z;
            }

        // cross product (v-tiles Rn = 2v+h share lane/reg positions), cast f16.
        // Result is exactly the A-fragment of MFMA2: A[m=llo][k=4*lhi+j].
        v4h a2[6];
#pragma unroll
        for (int h = 0; h < 2; ++h)
#pragma unroll
            for (int j = 0; j < 4; ++j) {
                const float g10 = accg[0][h][j], g11 = accg[0][2 + h][j], g12 = accg[0][4 + h][j];
                const float g20 = accg[1][h][j], g21 = accg[1][2 + h][j], g22 = accg[1][4 + h][j];
                a2[h][j]     = (f16)(g11 * g22 - g12 * g21);
                a2[2 + h][j] = (f16)(g12 * g20 - g10 * g22);
                a2[4 + h][j] = (f16)(g10 * g21 - g11 * g20);
            }

        // MFMA2: CO accumulation over g
#pragma unroll
        for (int Rn = 0; Rn < 6; ++Rn) {
            coacc[Rn][0] = __builtin_amdgcn_mfma_f32_16x16x16f16(a2[Rn], b20, coacc[Rn][0], 0, 0, 0);
            coacc[Rn][1] = __builtin_amdgcn_mfma_f32_16x16x16f16(a2[Rn], b21, coacc[Rn][1], 0, 0, 0);
        }
    }

    // ---- reduce 4 waves' partial CO into LDS (deterministic staged sum)
    __syncthreads();
    for (int w = 0; w < 4; ++w) {
        if (wid == w) {
#pragma unroll
            for (int Rn = 0; Rn < 6; ++Rn)
#pragma unroll
                for (int t = 0; t < 2; ++t)
#pragma unroll
                    for (int j = 0; j < 4; ++j) {
                        const int row = Rn * 16 + lhi * 4 + j;
                        const int col = t * 16 + llo;
                        if (w == 0) cob[row * 32 + col] = coacc[Rn][t][j];
                        else        cob[row * 32 + col] += coacc[Rn][t][j];
                    }
        }
        __syncthreads();
    }

    // ---- epilogue: out[n, p*32+b, v, k] = sum_a co[v*32+a][k] * Wout[p,l_k,a,b]
    const float* Wop = Wouts + p * 5120;
    float* outp = out + (n * 96 + p * 32) * 75;
    for (int idx = tid; idx < 300; idx += 256) {
        const int vk = idx % 75, q = idx / 75;
        const int v = vk / 25, k = vk - v * 25;
        const int l = (k >= 16) ? 4 : (k >= 9) ? 3 : (k >= 4) ? 2 : (k >= 1) ? 1 : 0;
        const float* w = Wop + l * 1024 + q * 8;
        float acc[8];
#pragma unroll
        for (int b = 0; b < 8; ++b) acc[b] = 0.0f;
        for (int a = 0; a < 32; ++a) {
            const float cv = cob[(v * 32 + a) * 32 + k];
#pragma unroll
            for (int b = 0; b < 8; ++b) acc[b] += cv * w[a * 32 + b];
        }
#pragma unroll
        for (int b = 0; b < 8; ++b) outp[(q * 8 + b) * 75 + vk] = acc[b];
    }
}

extern "C" void kernel_launch(void* const* d_in, const int* in_sizes, int n_in,
                              void* d_out, int out_size, void* d_ws, size_t ws_size,
                              hipStream_t stream) {
    const float* x1 = (const float*)d_in[0];
    const float* x2 = (const float*)d_in[1];
    const float* W1s = (const float*)d_in[2];
    const float* W2s = (const float*)d_in[3];
    const float* Wouts = (const float*)d_in[4];
    const float* Y = (const float*)d_in[5];
    const float* qw = (const float*)d_in[6];
    float* out = (float*)d_out;

    f16* A1buf = (f16*)d_ws;
    f16* B2buf = (f16*)((char*)d_ws + 129024);

    if (ws_size >= 258048) {
        vg_prep<<<NGB, 64, 0, stream>>>(Y, qw, A1buf, B2buf);
        vg_main<true><<<1536, 256, 0, stream>>>(x1, x2, W1s, W2s, Wouts, Y, qw,
                                                A1buf, B2buf, out);
    } else {
        vg_main<false><<<1536, 256, 0, stream>>>(x1, x2, W1s, W2s, Wouts, Y, qw,
                                                 nullptr, nullptr, out);
    }
}